// Round 3
// baseline (58726.636 us; speedup 1.0000x reference)
//
#include <hip/hip_runtime.h>
#include <stdint.h>

#define BB 64
#define LL 512
#define EE 256
#define HH 256
#define HID2 512
#define G4 1024
#define MM (LL*BB)
#define CH 128                 // timesteps per chunk
#define MROWS (CH*BB)          // G rows per dir per chunk = 8192
#define NWG_SCAN 128
#define IMPOSSIBLE_V (-1e4f)

// ---------------- embedding gather: X[t*B+b][e] = emb[xs[b][t]][e] (f32) ----------------
__global__ __launch_bounds__(256) void k_embed(const int* __restrict__ xs,
                        const float* __restrict__ emb, float* __restrict__ X){
  int id = blockIdx.x*256 + threadIdx.x;        // MM*64 threads, 4 elems each
  if(id >= MM*64) return;
  int m  = id >> 6;
  int e4 = (id & 63) << 2;
  int t = m >> 6, b = m & 63;
  int tok = xs[b*LL + t];
  float4 ev = *(const float4*)&emb[(size_t)tok*EE + e4];
  *(float4*)&X[(size_t)m*EE + e4] = ev;
}

// ---------------- input GEMM (one time-chunk): G[dir][ml][j] = X[t0(dir)*B+ml][:].W[dir][j][:] + b ---
// grid (MROWS/128=64, 16, 2), block 256. A=f32, W=f32, G out f32.
__global__ __launch_bounds__(256) void k_ingemm(const float* __restrict__ X, int KD,
        const float* __restrict__ W, const float* __restrict__ bias,
        float* __restrict__ G, int t0d0, int t0d1){
  __shared__ float As[32*132];
  __shared__ float Bs[32*68];
  const int tid = threadIdx.x;
  const int m0 = blockIdx.x*128, j0 = blockIdx.y*64, dir = blockIdx.z;
  const int t0 = (dir==0) ? t0d0 : t0d1;
  const float* Wd = W + (size_t)dir*G4*KD;
  const float* Xg = X + (size_t)t0*BB*KD;       // global row base for this dir's chunk
  float acc[8][4];
  #pragma unroll
  for(int i=0;i<8;i++){
    #pragma unroll
    for(int j=0;j<4;j++) acc[i][j]=0.f;
  }
  const int tx = tid & 15, ty = tid >> 4;      // tx -> 4 j cols, ty -> 8 m rows
  const int lr = tid >> 3, lk = tid & 7;       // A loader
  const int bj = tid >> 2, bk = (tid & 3)*8;   // B loader
  for(int kt=0; kt<KD; kt+=32){
    #pragma unroll
    for(int rr=0; rr<4; rr++){
      float4 a = *(const float4*)&Xg[(size_t)(m0 + lr + rr*32)*KD + kt + lk*4];
      As[(lk*4+0)*132 + lr + rr*32] = a.x;
      As[(lk*4+1)*132 + lr + rr*32] = a.y;
      As[(lk*4+2)*132 + lr + rr*32] = a.z;
      As[(lk*4+3)*132 + lr + rr*32] = a.w;
    }
    {
      const float* wp = &Wd[(size_t)(j0 + bj)*KD + kt + bk];
      float4 w0 = *(const float4*)wp;
      float4 w1 = *(const float4*)(wp+4);
      Bs[(bk+0)*68 + bj] = w0.x;
      Bs[(bk+1)*68 + bj] = w0.y;
      Bs[(bk+2)*68 + bj] = w0.z;
      Bs[(bk+3)*68 + bj] = w0.w;
      Bs[(bk+4)*68 + bj] = w1.x;
      Bs[(bk+5)*68 + bj] = w1.y;
      Bs[(bk+6)*68 + bj] = w1.z;
      Bs[(bk+7)*68 + bj] = w1.w;
    }
    __syncthreads();
    #pragma unroll
    for(int k=0;k<32;k++){
      float bq[4], aq[8];
      *(float4*)bq     = *(const float4*)&Bs[k*68 + tx*4];
      *(float4*)aq     = *(const float4*)&As[k*132 + ty*8];
      *(float4*)(aq+4) = *(const float4*)&As[k*132 + ty*8 + 4];
      #pragma unroll
      for(int i=0;i<8;i++){
        #pragma unroll
        for(int j=0;j<4;j++)
          acc[i][j] += aq[i]*bq[j];
      }
    }
    __syncthreads();
  }
  #pragma unroll
  for(int i=0;i<8;i++){
    int m = m0 + ty*8 + i;
    #pragma unroll
    for(int j=0;j<4;j++){
      int jj = j0 + tx*4 + j;
      G[((size_t)dir*MROWS + m)*G4 + jj] = acc[i][j] + bias[dir*G4 + jj];
    }
  }
}

// ---------------- persistent LSTM scan, one time-chunk (both directions) ----------------
// grid dim3(64,2) = 128 wgs, 256 threads. wg w of dir owns hidden units u0..u0+3
// (gate rows {g*256+u}), c in regs (checkpointed to cbuf between chunks),
// h exchanged via parity-double-buffered hbuf (parity continuous across chunks, CH even).
__global__ __launch_bounds__(256) void k_scan(const float* __restrict__ G,
        const float* __restrict__ Whh, float* __restrict__ Xout,
        float* __restrict__ hbuf, float* __restrict__ cbuf,
        int* __restrict__ bar, int barIdx, int chunk, int first){
  __shared__ float Hs[128*64];   // half of h, [k_local][b]
  __shared__ float Ws[16*256];   // this wg's 16 gate rows of Whh, [r][k]
  __shared__ float Gt[64*17];    // gate exchange [b][r]
  const int dir = blockIdx.y, w = blockIdx.x;
  const int tid = threadIdx.x;
  const int u0 = w*4;
  for(int i=tid; i<16*256; i+=256){
    int r = i >> 8, k = i & 255;
    int R = ((r>>2)<<8) + u0 + (r&3);
    Ws[i] = Whh[((size_t)dir*G4 + R)*HH + k];
  }
  for(int i=tid; i<128*64; i+=256) Hs[i] = 0.f;
  __syncthreads();
  const int bp_ = tid & 31, rp = tid >> 5;
  const int b0v = bp_*2;
  const int r0 = rp*2, r1 = r0+1;
  const int R0 = ((r0>>2)<<8) + u0 + (r0&3);
  const int R1 = ((r1>>2)<<8) + u0 + (r1&3);
  const int bn = tid & 63, uu = tid >> 6;
  float creg = first ? 0.f : cbuf[((size_t)dir*HH + u0 + uu)*BB + bn];
  int* cnt = bar + barIdx;
  for(int it=0; it<CH; it++){
    const int t  = (dir==0) ? (chunk*CH + it) : (LL-1 - chunk*CH - it);
    const int lt = (dir==0) ? it : (CH-1-it);
    const float* Gd = G + ((size_t)dir*MROWS + (size_t)lt*BB + b0v)*G4;
    const float gb00 = Gd[R0];
    const float gb01 = Gd[R1];
    const float gb10 = Gd[G4 + R0];
    const float gb11 = Gd[G4 + R1];
    float a00=0.f, a01=0.f, a10=0.f, a11=0.f;
    const float* hb = hbuf + ((size_t)((dir<<1) + ((it+1)&1)))*(HH*BB); // parity of it-1
    for(int half=0; half<2; half++){
      if(it > 0 || !first){
        __syncthreads();
        #pragma unroll 8
        for(int i=0;i<32;i++) Hs[i*256 + tid] = hb[half*8192 + i*256 + tid];
        __syncthreads();
      }
      const int kc = half*128;
      #pragma unroll 8
      for(int kl=0; kl<128; kl+=2){
        float2 h0 = *(const float2*)&Hs[kl*64 + b0v];
        float2 h1 = *(const float2*)&Hs[(kl+1)*64 + b0v];
        float2 w0 = *(const float2*)&Ws[r0*256 + kc + kl];
        float2 w1 = *(const float2*)&Ws[r1*256 + kc + kl];
        a00 += h0.x*w0.x + h1.x*w0.y;
        a01 += h0.x*w1.x + h1.x*w1.y;
        a10 += h0.y*w0.x + h1.y*w0.y;
        a11 += h0.y*w1.x + h1.y*w1.y;
      }
    }
    Gt[b0v*17 + r0]     = a00 + gb00;
    Gt[b0v*17 + r1]     = a01 + gb01;
    Gt[(b0v+1)*17 + r0] = a10 + gb10;
    Gt[(b0v+1)*17 + r1] = a11 + gb11;
    __syncthreads();
    {
      float gi = Gt[bn*17 + uu];
      float gf = Gt[bn*17 + 4 + uu];
      float gg = Gt[bn*17 + 8 + uu];
      float go = Gt[bn*17 + 12 + uu];
      float si = 1.f/(1.f + expf(-gi));
      float sf = 1.f/(1.f + expf(-gf));
      float so = 1.f/(1.f + expf(-go));
      creg = sf*creg + si*tanhf(gg);
      float hv = so*tanhf(creg);
      float* hw = hbuf + ((size_t)((dir<<1) + (it&1)))*(HH*BB);
      hw[(u0+uu)*BB + bn] = hv;
      Xout[((size_t)t*BB + bn)*HID2 + dir*HH + u0 + uu] = hv;
    }
    if(it < CH-1){
      __threadfence();
      __syncthreads();
      if(tid == 0){
        __hip_atomic_fetch_add(cnt, 1, __ATOMIC_RELEASE, __HIP_MEMORY_SCOPE_AGENT);
        const int target = NWG_SCAN*(it+1);
        int spins = 0;
        while(__hip_atomic_load(cnt, __ATOMIC_ACQUIRE, __HIP_MEMORY_SCOPE_AGENT) < target){
          __builtin_amdgcn_s_sleep(8);
          if(++spins > 20000) break;   // safety valve: never hang the queue
        }
      }
      __syncthreads();
    }
  }
  cbuf[((size_t)dir*HH + u0 + uu)*BB + bn] = creg;   // checkpoint c for next chunk
}

// ---------------- emissions: E[m][c] = feat[m][:] . Wfc[c][:] + bfc[c] ----------------
__global__ __launch_bounds__(256) void k_emit(const float* __restrict__ X,
        const float* __restrict__ Wfc, const float* __restrict__ bfc,
        float* __restrict__ E){
  __shared__ float Wf[5*520];
  int tid = threadIdx.x;
  for(int i=tid;i<5*512;i+=256){ int c=i>>9, k=i&511; Wf[c*520+k]=Wfc[c*512+k]; }
  __syncthreads();
  int mr = tid >> 3, c = tid & 7;
  int m = blockIdx.x*32 + mr;
  if(c < 5){
    float a = 0.f;
    const float* xr = &X[(size_t)m*HID2];
    #pragma unroll 4
    for(int k=0;k<512;k++) a += xr[k]*Wf[c*520+k];
    E[(size_t)m*8 + c] = a + bfc[c];
  }
}

// ---------------- features transpose to output ([t][b][h] -> [b][t][h] f32) + masks ----------------
__global__ __launch_bounds__(256) void k_feat(const float* __restrict__ X,
        float* __restrict__ feat, float* __restrict__ masks){
  size_t id = (size_t)blockIdx.x*256 + threadIdx.x;
  if(id >= (size_t)MM*HID2) return;
  int h = (int)(id & 511);
  size_t bt = id >> 9;
  int t = (int)(bt & 511);
  int b = (int)(bt >> 9);
  feat[id] = X[((size_t)t*BB + b)*HID2 + h];
  if(id < MM) masks[id] = 1.0f;
}

// ---------------- Viterbi: 1 block, 64 threads (one per batch) ----------------
__global__ __launch_bounds__(64) void k_viterbi(const float* __restrict__ E,
        const float* __restrict__ trans, float* __restrict__ out_score,
        float* __restrict__ out_tags){
  __shared__ uint16_t bps[LL*BB];   // packed backpointers, 64 KB
  const int b = threadIdx.x;
  float T[25];
  #pragma unroll
  for(int i=0;i<25;i++) T[i] = trans[i];
  float ms[5];
  #pragma unroll
  for(int c=0;c<5;c++) ms[c] = IMPOSSIBLE_V;
  ms[3] = 0.f;                       // START = 3
  for(int t=0;t<LL;t++){
    const float* e = &E[(size_t)(t*BB + b)*8];
    float ee[5];
    #pragma unroll
    for(int c=0;c<5;c++) ee[c] = e[c];
    float ns[5]; int pack = 0;
    #pragma unroll
    for(int to=0;to<5;to++){
      float best = ms[0] + T[to*5+0]; int bi = 0;
      #pragma unroll
      for(int f=1;f<5;f++){
        float v = ms[f] + T[to*5+f];
        if(v > best){ best = v; bi = f; }   // strict > keeps first-max (jnp.argmax semantics)
      }
      ns[to] = best + ee[to];
      pack |= bi << (3*to);
    }
    bps[t*BB + b] = (uint16_t)pack;
    #pragma unroll
    for(int c=0;c<5;c++) ms[c] = ns[c];
  }
  float best = ms[0] + T[4*5+0]; int tag = 0;   // STOP = 4
  #pragma unroll
  for(int f=1;f<5;f++){
    float v = ms[f] + T[4*5+f];
    if(v > best){ best = v; tag = f; }
  }
  out_score[b] = best;
  out_tags[b*LL + (LL-1)] = (float)tag;
  for(int t=LL-1; t>=1; t--){
    tag = (bps[t*BB + b] >> (3*tag)) & 7;
    out_tags[b*LL + t-1] = (float)tag;
  }
}

extern "C" void kernel_launch(void* const* d_in, const int* in_sizes, int n_in,
                              void* d_out, int out_size, void* d_ws, size_t ws_size,
                              hipStream_t stream){
  const int*   xs    = (const int*)d_in[0];
  const float* emb   = (const float*)d_in[1];
  const float* Wih0  = (const float*)d_in[2];
  const float* Whh0  = (const float*)d_in[3];
  const float* b0    = (const float*)d_in[4];
  const float* WihL  = (const float*)d_in[5];
  const float* WhhL  = (const float*)d_in[6];
  const float* bL    = (const float*)d_in[7];
  const float* Wfc   = (const float*)d_in[8];
  const float* bfc   = (const float*)d_in[9];
  const float* trans = (const float*)d_in[10];

  char* ws = (char*)d_ws;
  int*   bar  = (int*)ws;                                     // 16 counters (layer*4+chunk)
  float* hbuf = (float*)(ws + 1024);                          // 2 dir x 2 parity x HH*BB f32 = 256 KiB
  float* cbuf = (float*)(ws + 1024 + (size_t)262144);         // 2 x HH x BB f32 = 128 KiB
  float* Xa   = (float*)(ws + (size_t)(1<<20));               // 64 MiB
  float* Xb   = (float*)(ws + (size_t)(1<<20) + ((size_t)MM*HID2*4));           // 64 MiB
  float* G    = (float*)(ws + (size_t)(1<<20) + 2*((size_t)MM*HID2*4));         // 2*MROWS*G4 f32 = 64 MiB
  float* emitb = G;                                           // alias: G dead after last scan

  hipMemsetAsync(bar, 0, 1024, stream);
  k_embed<<<8192, 256, 0, stream>>>(xs, emb, Xa);
  float* cur = Xa; float* nxt = Xb;
  for(int l=0;l<4;l++){
    int KD = (l==0) ? 256 : 512;
    const float* Wih = (l==0) ? Wih0 : WihL + (size_t)(l-1)*2*G4*HID2;
    const float* Whh = (l==0) ? Whh0 : WhhL + (size_t)(l-1)*2*G4*HH;
    const float* bb  = (l==0) ? b0   : bL  + (size_t)(l-1)*2*G4;
    for(int chunk=0; chunk<4; chunk++){
      int t0d0 = chunk*CH;
      int t0d1 = (LL-CH) - chunk*CH;
      k_ingemm<<<dim3(MROWS/128, G4/64, 2), 256, 0, stream>>>(cur, KD, Wih, bb, G, t0d0, t0d1);
      k_scan<<<dim3(64, 2), 256, 0, stream>>>(G, Whh, nxt, hbuf, cbuf, bar,
                                              l*4+chunk, chunk, chunk==0 ? 1 : 0);
    }
    float* tmp = cur; cur = nxt; nxt = tmp;
  }
  k_emit<<<MM/32, 256, 0, stream>>>(cur, Wfc, bfc, emitb);
  float* out       = (float*)d_out;
  float* out_score = out;
  float* out_tags  = out + 64;
  float* out_feat  = out + 64 + MM;
  float* out_masks = out + 64 + MM + (size_t)MM*HID2;
  k_feat<<<(MM*HID2)/256, 256, 0, stream>>>(cur, out_feat, out_masks);
  k_viterbi<<<1, 64, 0, stream>>>(emitb, trans, out_score, out_tags);
}

// Round 4
// 52409.436 us; speedup vs baseline: 1.1205x; 1.1205x over previous
//
#include <hip/hip_runtime.h>
#include <stdint.h>

#define BB 64
#define LL 512
#define EE 256
#define HH 256
#define HID2 512
#define G4 1024
#define MM (LL*BB)          // 32768
#define CH 128
#define MROWS (CH*BB)       // 8192
#define IMPOSSIBLE_V (-1e4f)

// ---------------- embed: Xt[e][m] = emb[xs[b][t]][e], m = t*64+b ----------------
__global__ __launch_bounds__(256) void k_embed(const int* __restrict__ xs,
      const float* __restrict__ emb, float* __restrict__ Xt){
  int id = blockIdx.x*256 + threadIdx.x;      // MM*64 threads
  int m  = id & (MM-1);
  int e4 = (id >> 15) << 2;
  int t = m >> 6, b = m & 63;
  int tok = xs[b*LL + t];
  float4 v = *(const float4*)&emb[(size_t)tok*EE + e4];
  Xt[(size_t)(e4+0)*MM + m] = v.x;
  Xt[(size_t)(e4+1)*MM + m] = v.y;
  Xt[(size_t)(e4+2)*MM + m] = v.z;
  Xt[(size_t)(e4+3)*MM + m] = v.w;
}

// ---------------- input GEMM: Gt[dir][j][ml] = sum_k Xt[k][t0*64+ml]*W[dir][j][k] + bias ----
// grid (64, 16, 2), block 256
__global__ __launch_bounds__(256) void k_ingemm(const float* __restrict__ Xt, int KD,
      const float* __restrict__ W, const float* __restrict__ bias,
      float* __restrict__ G, int t0d0, int t0d1){
  __shared__ float As[32*132];
  __shared__ float Bs[32*68];
  const int tid = threadIdx.x;
  const int m0 = blockIdx.x*128, j0 = blockIdx.y*64, dir = blockIdx.z;
  const int t0 = (dir==0) ? t0d0 : t0d1;
  const float* Wd = W + (size_t)dir*G4*KD;
  const float* Xg = Xt + (size_t)t0*BB;       // column base for this dir's chunk
  float acc[8][4];
  #pragma unroll
  for(int i=0;i<8;i++){
    #pragma unroll
    for(int j=0;j<4;j++) acc[i][j]=0.f;
  }
  const int tx = tid & 15, ty = tid >> 4;
  const int kr = tid >> 3, mq = tid & 7;      // A loader: k-row, m-quad
  const int bj = tid >> 2, bk = (tid & 3)*8;  // B loader
  for(int kt=0; kt<KD; kt+=32){
    #pragma unroll
    for(int i=0;i<4;i++){
      float4 a = *(const float4*)&Xg[(size_t)(kt+kr)*MM + m0 + mq*16 + i*4];
      *(float4*)&As[kr*132 + mq*16 + i*4] = a;
    }
    {
      const float* wp = &Wd[(size_t)(j0 + bj)*KD + kt + bk];
      float4 w0 = *(const float4*)wp;
      float4 w1 = *(const float4*)(wp+4);
      Bs[(bk+0)*68 + bj] = w0.x;
      Bs[(bk+1)*68 + bj] = w0.y;
      Bs[(bk+2)*68 + bj] = w0.z;
      Bs[(bk+3)*68 + bj] = w0.w;
      Bs[(bk+4)*68 + bj] = w1.x;
      Bs[(bk+5)*68 + bj] = w1.y;
      Bs[(bk+6)*68 + bj] = w1.z;
      Bs[(bk+7)*68 + bj] = w1.w;
    }
    __syncthreads();
    #pragma unroll
    for(int k=0;k<32;k++){
      float bq[4], aq[8];
      *(float4*)bq     = *(const float4*)&Bs[k*68 + tx*4];
      *(float4*)aq     = *(const float4*)&As[k*132 + ty*8];
      *(float4*)(aq+4) = *(const float4*)&As[k*132 + ty*8 + 4];
      #pragma unroll
      for(int i=0;i<8;i++){
        #pragma unroll
        for(int j=0;j<4;j++)
          acc[i][j] += aq[i]*bq[j];
      }
    }
    __syncthreads();
  }
  #pragma unroll
  for(int j=0;j<4;j++){
    int jj = j0 + tx*4 + j;
    float bb_ = bias[dir*G4 + jj];
    float* q = &G[((size_t)dir*G4 + jj)*MROWS + m0 + ty*8];
    float4 v0 = {acc[0][j]+bb_, acc[1][j]+bb_, acc[2][j]+bb_, acc[3][j]+bb_};
    float4 v1 = {acc[4][j]+bb_, acc[5][j]+bb_, acc[6][j]+bb_, acc[7][j]+bb_};
    *(float4*)q = v0;
    *(float4*)(q+4) = v1;
  }
}

// ---------------- persistent LSTM scan, one time-chunk, both directions ----------------
// grid dim3(64,2), block 256. wg w of dir owns hidden units u0..u0+3 (16 gate rows).
// Whh slice lives in VGPRs (4 rows x 32 k per thread). h exchanged via parity
// hbuf + per-wg flag lines (no contended counter). S (64KB LDS) is time-shared:
//   stage/gemm: Hs[k][b] (swizzled f4 chunks), then scr partials, then Gt gates.
__global__ __launch_bounds__(256,1) void k_scan(const float* __restrict__ G,
      const float* __restrict__ Whh, float* __restrict__ Xout,
      float* __restrict__ hbuf, float* __restrict__ cbuf,
      int* __restrict__ flags, int chunk, int sbase, int first){
  __shared__ float S[16384];
  float4* S4 = (float4*)S;
  const int dir = blockIdx.y, w = blockIdx.x, tid = threadIdx.x;
  const int u0 = w*4;
  const int ks = tid>>5, rp = (tid>>3)&3, bg = tid&7;   // gemm role
  const int ui = tid>>6, bn = tid&63;                    // activation role
  const int r2 = tid>>4, b2c = tid&15;                   // phase-2 role (out f4 = tid)
  const int R2 = (r2>>2)*256 + u0 + (r2&3);
  // Whh rows r = rp*4+ri -> global row R = rp*256 + u0 + ri ; k = kk*8 + ks
  float Wreg[4][32];
  #pragma unroll
  for(int ri=0;ri<4;ri++){
    const float* wsrc = &Whh[((size_t)dir*G4 + rp*256 + u0 + ri)*HH + ks];
    #pragma unroll
    for(int kk=0;kk<32;kk++) Wreg[ri][kk] = wsrc[kk*8];
  }
  float creg = first ? 0.f : cbuf[((size_t)dir*HH + u0+ui)*BB + bn];
  if(first){
    #pragma unroll
    for(int i=0;i<64;i++) S[i*256 + tid] = 0.f;
  }
  __syncthreads();
  const int rotH = 3*(ks&1);
  for(int it=0; it<CH; it++){
    const int sg = sbase + it;
    const int t  = (dir==0) ? (chunk*CH + it) : (LL-1 - chunk*CH - it);
    const int lt = (dir==0) ? it : (CH-1-it);
    // prefetch this thread's gate-bias chunk (consumed after reduction)
    float4 gpre = *(const float4*)&G[((size_t)dir*G4 + R2)*MROWS + (size_t)lt*BB + b2c*4];
    if(!(first && it==0)){
      if(tid < 64){
        int* fp = &flags[(dir*64 + tid)*16];
        int spins = 0;
        while(__hip_atomic_load(fp, __ATOMIC_RELAXED, __HIP_MEMORY_SCOPE_AGENT) < sg){
          __builtin_amdgcn_s_sleep(1);
          if(++spins > (1<<22)) break;   // safety valve: never hang
        }
        __threadfence();                  // acquire: invalidate L1, order loads
      }
      __syncthreads();
      // stage h (16384 floats) into swizzled Hs
      const float4* hb4 = (const float4*)&hbuf[(size_t)(((sg+1)&1)*2 + dir)*(HH*BB)];
      #pragma unroll
      for(int i=0;i<16;i++){
        float4 v = hb4[i*256 + tid];
        int k = i*16 + (tid>>4);
        int c = tid & 15;
        S4[k*16 + ((c + 3*(k&1)) & 15)] = v;
      }
      __syncthreads();
    }
    // gate GEMM: acc[ri][bi] over k-slice {ks, 8+ks, ..., 248+ks}
    float acc[4][8];
    #pragma unroll
    for(int ri=0;ri<4;ri++){
      #pragma unroll
      for(int bi=0;bi<8;bi++) acc[ri][bi]=0.f;
    }
    #pragma unroll
    for(int kk=0;kk<32;kk++){
      const int k = kk*8 + ks;
      float4 hA = S4[k*16 + ((bg*2     + rotH) & 15)];
      float4 hB = S4[k*16 + ((bg*2 + 1 + rotH) & 15)];
      #pragma unroll
      for(int ri=0;ri<4;ri++){
        const float wv = Wreg[ri][kk];
        acc[ri][0] += wv*hA.x; acc[ri][1] += wv*hA.y;
        acc[ri][2] += wv*hA.z; acc[ri][3] += wv*hA.w;
        acc[ri][4] += wv*hB.x; acc[ri][5] += wv*hB.y;
        acc[ri][6] += wv*hB.z; acc[ri][7] += wv*hB.w;
      }
    }
    __syncthreads();                       // Hs dead; S becomes scr
    #pragma unroll
    for(int ri=0;ri<4;ri++){
      const int r = rp*4 + ri;
      float4 lo = {acc[ri][0],acc[ri][1],acc[ri][2],acc[ri][3]};
      float4 hi = {acc[ri][4],acc[ri][5],acc[ri][6],acc[ri][7]};
      S4[ks*256 + r*16 + ((bg*2     + 3*ks) & 15)] = lo;
      S4[ks*256 + r*16 + ((bg*2 + 1 + 3*ks) & 15)] = hi;
    }
    __syncthreads();
    float4 g4 = gpre;
    #pragma unroll
    for(int q=0;q<8;q++){
      float4 p = S4[q*256 + r2*16 + ((b2c + 3*q) & 15)];
      g4.x += p.x; g4.y += p.y; g4.z += p.z; g4.w += p.w;
    }
    S4[2048 + tid] = g4;                   // Gt at S[8192..9215], disjoint from scr
    __syncthreads();
    // activation: thread (ui, bn)
    {
      float gi = S[8192 + (     ui)*64 + bn];
      float gf = S[8192 + ( 4 + ui)*64 + bn];
      float gg = S[8192 + ( 8 + ui)*64 + bn];
      float go = S[8192 + (12 + ui)*64 + bn];
      float si = 1.f/(1.f + expf(-gi));
      float sf = 1.f/(1.f + expf(-gf));
      float so = 1.f/(1.f + expf(-go));
      creg = sf*creg + si*tanhf(gg);
      float hv = so*tanhf(creg);
      hbuf[(size_t)((sg&1)*2 + dir)*(HH*BB) + (u0+ui)*BB + bn] = hv;
      Xout[(size_t)(dir*HH + u0+ui)*MM + (size_t)t*BB + bn] = hv;
    }
    __threadfence();
    __syncthreads();
    if(tid==0)
      __hip_atomic_store(&flags[(dir*64 + w)*16], sg+1,
                         __ATOMIC_RELEASE, __HIP_MEMORY_SCOPE_AGENT);
  }
  cbuf[((size_t)dir*HH + u0+ui)*BB + bn] = creg;
}

// ---------------- emissions from Xt: E[m][c] ----------------
__global__ __launch_bounds__(256) void k_emit(const float* __restrict__ Xt,
      const float* __restrict__ Wfc, const float* __restrict__ bfc, float* __restrict__ E){
  __shared__ float Wf[5*512];
  int tid = threadIdx.x;
  for(int i=tid;i<5*512;i+=256) Wf[i] = Wfc[i];
  __syncthreads();
  int m = blockIdx.x*256 + tid;
  float a0=0,a1=0,a2=0,a3=0,a4=0;
  #pragma unroll 4
  for(int k=0;k<512;k++){
    float x = Xt[(size_t)k*MM + m];
    a0 += x*Wf[k]; a1 += x*Wf[512+k]; a2 += x*Wf[1024+k]; a3 += x*Wf[1536+k]; a4 += x*Wf[2048+k];
  }
  float* e = &E[(size_t)m*8];
  e[0]=a0+bfc[0]; e[1]=a1+bfc[1]; e[2]=a2+bfc[2]; e[3]=a3+bfc[3]; e[4]=a4+bfc[4];
}

// ---------------- features: feat[b][t][h] = Xt[h][t*64+b] (tile transpose) ----------------
__global__ __launch_bounds__(256) void k_feat(const float* __restrict__ Xt,
      float* __restrict__ feat){
  __shared__ float T[64][65];
  const int t = blockIdx.y, h0 = blockIdx.x*64;
  const int tid = threadIdx.x;
  const int hr = tid>>2, q = tid&3;
  const float* src = &Xt[(size_t)(h0+hr)*MM + (size_t)t*BB + q*16];
  #pragma unroll
  for(int i=0;i<4;i++){
    float4 v = *(const float4*)&src[i*4];
    T[hr][q*16+i*4+0]=v.x; T[hr][q*16+i*4+1]=v.y;
    T[hr][q*16+i*4+2]=v.z; T[hr][q*16+i*4+3]=v.w;
  }
  __syncthreads();
  float* dst = &feat[((size_t)hr*LL + t)*HID2 + h0 + q*16];
  #pragma unroll
  for(int i=0;i<16;i+=4){
    float4 v = {T[q*16+i+0][hr], T[q*16+i+1][hr], T[q*16+i+2][hr], T[q*16+i+3][hr]};
    *(float4*)&dst[i] = v;
  }
}

__global__ __launch_bounds__(256) void k_mask(float* __restrict__ masks){
  int id = blockIdx.x*256 + threadIdx.x;
  if(id < MM) masks[id] = 1.0f;
}

// ---------------- Viterbi: 1 block, 64 threads, prefetch-pipelined ----------------
__global__ __launch_bounds__(64) void k_viterbi(const float* __restrict__ E,
      const float* __restrict__ trans, float* __restrict__ out_score,
      float* __restrict__ out_tags){
  __shared__ uint16_t bps[LL*BB];
  const int b = threadIdx.x;
  float T[25];
  #pragma unroll
  for(int i=0;i<25;i++) T[i] = trans[i];
  float ms[5];
  #pragma unroll
  for(int c=0;c<5;c++) ms[c] = IMPOSSIBLE_V;
  ms[3] = 0.f;                               // START = 3
  float4 c0 = *(const float4*)&E[(size_t)b*8];
  float  c4 = E[(size_t)b*8 + 4];
  for(int t=0;t<LL;t++){
    float4 n0 = c0; float n4 = c4;
    if(t < LL-1){
      const float* e = &E[(size_t)((t+1)*BB + b)*8];
      n0 = *(const float4*)e; n4 = e[4];
    }
    float ee[5] = {c0.x, c0.y, c0.z, c0.w, c4};
    float ns[5]; int pack = 0;
    #pragma unroll
    for(int to=0;to<5;to++){
      float best = ms[0] + T[to*5+0]; int bi = 0;
      #pragma unroll
      for(int f=1;f<5;f++){
        float v = ms[f] + T[to*5+f];
        if(v > best){ best = v; bi = f; }   // strict > = first-max (jnp.argmax)
      }
      ns[to] = best + ee[to];
      pack |= bi << (3*to);
    }
    bps[t*BB + b] = (uint16_t)pack;
    #pragma unroll
    for(int c=0;c<5;c++) ms[c] = ns[c];
    c0 = n0; c4 = n4;
  }
  float best = ms[0] + T[4*5+0]; int tag = 0; // STOP = 4
  #pragma unroll
  for(int f=1;f<5;f++){
    float v = ms[f] + T[4*5+f];
    if(v > best){ best = v; tag = f; }
  }
  out_score[b] = best;
  out_tags[b*LL + (LL-1)] = (float)tag;
  for(int t=LL-1; t>=1; t--){
    tag = (bps[t*BB + b] >> (3*tag)) & 7;
    out_tags[b*LL + t-1] = (float)tag;
  }
}

extern "C" void kernel_launch(void* const* d_in, const int* in_sizes, int n_in,
                              void* d_out, int out_size, void* d_ws, size_t ws_size,
                              hipStream_t stream){
  const int*   xs    = (const int*)d_in[0];
  const float* emb   = (const float*)d_in[1];
  const float* Wih0  = (const float*)d_in[2];
  const float* Whh0  = (const float*)d_in[3];
  const float* b0    = (const float*)d_in[4];
  const float* WihL  = (const float*)d_in[5];
  const float* WhhL  = (const float*)d_in[6];
  const float* bL    = (const float*)d_in[7];
  const float* Wfc   = (const float*)d_in[8];
  const float* bfc   = (const float*)d_in[9];
  const float* trans = (const float*)d_in[10];

  char* ws = (char*)d_ws;
  int*   flags = (int*)ws;                                   // 2*64*16 ints = 8 KB
  float* hbuf  = (float*)(ws + 32768);                       // 4 * 16384 f32 = 256 KB
  float* cbuf  = (float*)(ws + 32768 + 262144);              // 2*256*64 f32 = 128 KB
  float* Xa    = (float*)(ws + (size_t)(1<<20));                             // 64 MB
  float* Xb    = (float*)(ws + (size_t)(1<<20) + ((size_t)MM*HID2*4));       // 64 MB
  float* G     = (float*)(ws + (size_t)(1<<20) + 2*((size_t)MM*HID2*4));     // 64 MB
  float* emitb = G;                                          // alias: G dead after scans

  hipMemsetAsync(flags, 0, 8192, stream);
  k_embed<<<8192, 256, 0, stream>>>(xs, emb, Xa);
  float* cur = Xa; float* nxt = Xb;
  for(int l=0;l<4;l++){
    int KD = (l==0) ? 256 : 512;
    const float* Wih = (l==0) ? Wih0 : WihL + (size_t)(l-1)*2*G4*HID2;
    const float* Whh = (l==0) ? Whh0 : WhhL + (size_t)(l-1)*2*G4*HH;
    const float* bb  = (l==0) ? b0   : bL  + (size_t)(l-1)*2*G4;
    for(int chunk=0; chunk<4; chunk++){
      int t0d0 = chunk*CH;
      int t0d1 = (LL-CH) - chunk*CH;
      k_ingemm<<<dim3(MROWS/128, G4/64, 2), 256, 0, stream>>>(cur, KD, Wih, bb, G, t0d0, t0d1);
      k_scan<<<dim3(64, 2), 256, 0, stream>>>(G, Whh, nxt, hbuf, cbuf, flags,
                                              chunk, (l*4+chunk)*CH, chunk==0 ? 1 : 0);
    }
    float* tmp = cur; cur = nxt; nxt = tmp;
  }
  k_emit<<<MM/256, 256, 0, stream>>>(cur, Wfc, bfc, emitb);
  float* out       = (float*)d_out;
  float* out_score = out;
  float* out_tags  = out + 64;
  float* out_feat  = out + 64 + MM;
  float* out_masks = out + 64 + MM + (size_t)MM*HID2;
  k_feat<<<dim3(HID2/64, LL), 256, 0, stream>>>(cur, out_feat);
  k_mask<<<MM/256, 256, 0, stream>>>(out_masks);
  k_viterbi<<<1, 64, 0, stream>>>(emitb, trans, out_score, out_tags);
}

// Round 5
// 33944.638 us; speedup vs baseline: 1.7301x; 1.5440x over previous
//
#include <hip/hip_runtime.h>
#include <stdint.h>

#define BB 64
#define LL 512
#define EE 256
#define HH 256
#define HID2 512
#define G4 1024
#define MM (LL*BB)          // 32768
#define CH 128
#define MROWS (CH*BB)       // 8192
#define IMPOSSIBLE_V (-1e4f)

__device__ __forceinline__ void agent_store_f32(float* p, float v){
  __hip_atomic_store(p, v, __ATOMIC_RELAXED, __HIP_MEMORY_SCOPE_AGENT);
}
__device__ __forceinline__ uint64_t agent_load_u64(const uint64_t* p){
  return __hip_atomic_load(p, __ATOMIC_RELAXED, __HIP_MEMORY_SCOPE_AGENT);
}

// ---------------- embed: Xt[e][m] = emb[xs[b][t]][e], m = t*64+b ----------------
__global__ __launch_bounds__(256) void k_embed(const int* __restrict__ xs,
      const float* __restrict__ emb, float* __restrict__ Xt){
  int id = blockIdx.x*256 + threadIdx.x;      // MM*64 threads
  int m  = id & (MM-1);
  int e4 = (id >> 15) << 2;
  int t = m >> 6, b = m & 63;
  int tok = xs[b*LL + t];
  float4 v = *(const float4*)&emb[(size_t)tok*EE + e4];
  Xt[(size_t)(e4+0)*MM + m] = v.x;
  Xt[(size_t)(e4+1)*MM + m] = v.y;
  Xt[(size_t)(e4+2)*MM + m] = v.z;
  Xt[(size_t)(e4+3)*MM + m] = v.w;
}

// ---------------- input GEMM: Gt[dir][j][ml] = sum_k Xt[k][t0*64+ml]*W[dir][j][k] + bias ----
// grid (64, 16, 2), block 256
__global__ __launch_bounds__(256) void k_ingemm(const float* __restrict__ Xt, int KD,
      const float* __restrict__ W, const float* __restrict__ bias,
      float* __restrict__ G, int t0d0, int t0d1){
  __shared__ float As[32*132];
  __shared__ float Bs[32*68];
  const int tid = threadIdx.x;
  const int m0 = blockIdx.x*128, j0 = blockIdx.y*64, dir = blockIdx.z;
  const int t0 = (dir==0) ? t0d0 : t0d1;
  const float* Wd = W + (size_t)dir*G4*KD;
  const float* Xg = Xt + (size_t)t0*BB;       // column base for this dir's chunk
  float acc[8][4];
  #pragma unroll
  for(int i=0;i<8;i++){
    #pragma unroll
    for(int j=0;j<4;j++) acc[i][j]=0.f;
  }
  const int tx = tid & 15, ty = tid >> 4;
  const int kr = tid >> 3, mq = tid & 7;      // A loader: k-row, m-quad
  const int bj = tid >> 2, bk = (tid & 3)*8;  // B loader
  for(int kt=0; kt<KD; kt+=32){
    #pragma unroll
    for(int i=0;i<4;i++){
      float4 a = *(const float4*)&Xg[(size_t)(kt+kr)*MM + m0 + mq*16 + i*4];
      *(float4*)&As[kr*132 + mq*16 + i*4] = a;
    }
    {
      const float* wp = &Wd[(size_t)(j0 + bj)*KD + kt + bk];
      float4 w0 = *(const float4*)wp;
      float4 w1 = *(const float4*)(wp+4);
      Bs[(bk+0)*68 + bj] = w0.x;
      Bs[(bk+1)*68 + bj] = w0.y;
      Bs[(bk+2)*68 + bj] = w0.z;
      Bs[(bk+3)*68 + bj] = w0.w;
      Bs[(bk+4)*68 + bj] = w1.x;
      Bs[(bk+5)*68 + bj] = w1.y;
      Bs[(bk+6)*68 + bj] = w1.z;
      Bs[(bk+7)*68 + bj] = w1.w;
    }
    __syncthreads();
    #pragma unroll
    for(int k=0;k<32;k++){
      float bq[4], aq[8];
      *(float4*)bq     = *(const float4*)&Bs[k*68 + tx*4];
      *(float4*)aq     = *(const float4*)&As[k*132 + ty*8];
      *(float4*)(aq+4) = *(const float4*)&As[k*132 + ty*8 + 4];
      #pragma unroll
      for(int i=0;i<8;i++){
        #pragma unroll
        for(int j=0;j<4;j++)
          acc[i][j] += aq[i]*bq[j];
      }
    }
    __syncthreads();
  }
  #pragma unroll
  for(int j=0;j<4;j++){
    int jj = j0 + tx*4 + j;
    float bb_ = bias[dir*G4 + jj];
    float* q = &G[((size_t)dir*G4 + jj)*MROWS + m0 + ty*8];
    float4 v0 = {acc[0][j]+bb_, acc[1][j]+bb_, acc[2][j]+bb_, acc[3][j]+bb_};
    float4 v1 = {acc[4][j]+bb_, acc[5][j]+bb_, acc[6][j]+bb_, acc[7][j]+bb_};
    *(float4*)q = v0;
    *(float4*)(q+4) = v1;
  }
}

// ---------------- persistent LSTM scan, one time-chunk, both directions ----------------
// grid dim3(64,2), block 256. wg w of dir owns hidden units u0..u0+3 (16 gate rows).
// Whh slice in VGPRs. h exchanged via RELAXED agent-scope atomics (write-through /
// read-through at the coherence point) — no threadfence (no buffer_wbl2/buffer_inv)
// anywhere in the step loop. Ordering: h stores -> s_waitcnt(0) -> syncthreads ->
// relaxed flag store; consumer polls flag then issues read-through h loads.
__global__ __launch_bounds__(256,1) void k_scan(const float* __restrict__ G,
      const float* __restrict__ Whh, float* __restrict__ Xout,
      float* __restrict__ hbuf, float* __restrict__ cbuf,
      int* __restrict__ flags, int chunk, int sbase, int first){
  __shared__ float S[16384];
  float4* S4 = (float4*)S;
  const int dir = blockIdx.y, w = blockIdx.x, tid = threadIdx.x;
  const int u0 = w*4;
  const int ks = tid>>5, rp = (tid>>3)&3, bg = tid&7;   // gemm role
  const int ui = tid>>6, bn = tid&63;                    // activation role
  const int r2 = tid>>4, b2c = tid&15;                   // reduce role (out f4 = tid)
  const int R2 = (r2>>2)*256 + u0 + (r2&3);
  // Whh rows r = rp*4+ri -> global row R = rp*256 + u0 + ri ; k = kk*8 + ks
  float Wreg[4][32];
  #pragma unroll
  for(int ri=0;ri<4;ri++){
    const float* wsrc = &Whh[((size_t)dir*G4 + rp*256 + u0 + ri)*HH + ks];
    #pragma unroll
    for(int kk=0;kk<32;kk++) Wreg[ri][kk] = wsrc[kk*8];
  }
  float creg = first ? 0.f : cbuf[((size_t)dir*HH + u0+ui)*BB + bn];
  if(first){
    #pragma unroll
    for(int i=0;i<64;i++) S[i*256 + tid] = 0.f;
  }
  __syncthreads();
  const int rotH = 3*(ks&1);
  for(int it=0; it<CH; it++){
    const int sg = sbase + it;
    const int t  = (dir==0) ? (chunk*CH + it) : (LL-1 - chunk*CH - it);
    const int lt = (dir==0) ? it : (CH-1-it);
    // prefetch this thread's gate-bias chunk (consumed after reduction)
    float4 gpre = *(const float4*)&G[((size_t)dir*G4 + R2)*MROWS + (size_t)lt*BB + b2c*4];
    if(!(first && it==0)){
      if(tid < 64){
        int* fp = &flags[(dir*64 + tid)*16];
        int spins = 0;
        while(__hip_atomic_load(fp, __ATOMIC_RELAXED, __HIP_MEMORY_SCOPE_AGENT) < sg){
          __builtin_amdgcn_s_sleep(1);
          if(++spins > (1<<22)) break;   // safety valve: never hang
        }
      }
      __syncthreads();
      // stage h (16384 floats) into swizzled Hs via read-through 64-bit loads
      const uint64_t* hb8 = (const uint64_t*)&hbuf[(size_t)(((sg+1)&1)*2 + dir)*(HH*BB)];
      #pragma unroll
      for(int i=0;i<32;i++){
        uint64_t v8 = agent_load_u64(&hb8[i*256 + tid]);
        int f = (i*256 + tid)*2;        // float index = k*64 + b  (b even)
        int k = f >> 6, b = f & 63;
        union { uint64_t u; float f2[2]; } cv; cv.u = v8;
        int bs = (b + 12*(k&1)) & 63;   // same swizzle as float4: (c+3*(k&1))&15
        S[k*64 + bs]     = cv.f2[0];
        S[k*64 + bs + 1] = cv.f2[1];
      }
      __syncthreads();
    }
    // gate GEMM: acc[ri][bi] over k-slice {ks, 8+ks, ..., 248+ks}
    float acc[4][8];
    #pragma unroll
    for(int ri=0;ri<4;ri++){
      #pragma unroll
      for(int bi=0;bi<8;bi++) acc[ri][bi]=0.f;
    }
    #pragma unroll
    for(int kk=0;kk<32;kk++){
      const int k = kk*8 + ks;
      float4 hA = S4[k*16 + ((bg*2     + rotH) & 15)];
      float4 hB = S4[k*16 + ((bg*2 + 1 + rotH) & 15)];
      #pragma unroll
      for(int ri=0;ri<4;ri++){
        const float wv = Wreg[ri][kk];
        acc[ri][0] += wv*hA.x; acc[ri][1] += wv*hA.y;
        acc[ri][2] += wv*hA.z; acc[ri][3] += wv*hA.w;
        acc[ri][4] += wv*hB.x; acc[ri][5] += wv*hB.y;
        acc[ri][6] += wv*hB.z; acc[ri][7] += wv*hB.w;
      }
    }
    __syncthreads();                       // Hs dead; S becomes scr
    #pragma unroll
    for(int ri=0;ri<4;ri++){
      const int r = rp*4 + ri;
      float4 lo = {acc[ri][0],acc[ri][1],acc[ri][2],acc[ri][3]};
      float4 hi = {acc[ri][4],acc[ri][5],acc[ri][6],acc[ri][7]};
      S4[ks*256 + r*16 + ((bg*2     + 3*ks) & 15)] = lo;
      S4[ks*256 + r*16 + ((bg*2 + 1 + 3*ks) & 15)] = hi;
    }
    __syncthreads();
    float4 g4 = gpre;
    #pragma unroll
    for(int q=0;q<8;q++){
      float4 p = S4[q*256 + r2*16 + ((b2c + 3*q) & 15)];
      g4.x += p.x; g4.y += p.y; g4.z += p.z; g4.w += p.w;
    }
    S4[2048 + tid] = g4;                   // Gt at S[8192..9215], disjoint from scr
    __syncthreads();
    // activation: thread (ui, bn)
    {
      float gi = S[8192 + (     ui)*64 + bn];
      float gf = S[8192 + ( 4 + ui)*64 + bn];
      float gg = S[8192 + ( 8 + ui)*64 + bn];
      float go = S[8192 + (12 + ui)*64 + bn];
      float si = 1.f/(1.f + expf(-gi));
      float sf = 1.f/(1.f + expf(-gf));
      float so = 1.f/(1.f + expf(-go));
      creg = sf*creg + si*tanhf(gg);
      float hv = so*tanhf(creg);
      // write-through h store (visible at coherence point, no fence needed)
      agent_store_f32(&hbuf[(size_t)((sg&1)*2 + dir)*(HH*BB) + (u0+ui)*BB + bn], hv);
      Xout[(size_t)(dir*HH + u0+ui)*MM + (size_t)t*BB + bn] = hv;
    }
    __builtin_amdgcn_s_waitcnt(0);         // drain h stores (acked at coherence point)
    __syncthreads();                       // all 256 threads' stores drained
    if(tid==0)
      __hip_atomic_store(&flags[(dir*64 + w)*16], sg+1,
                         __ATOMIC_RELAXED, __HIP_MEMORY_SCOPE_AGENT);
  }
  cbuf[((size_t)dir*HH + u0+ui)*BB + bn] = creg;
}

// ---------------- emissions from Xt: E[m][c] ----------------
__global__ __launch_bounds__(256) void k_emit(const float* __restrict__ Xt,
      const float* __restrict__ Wfc, const float* __restrict__ bfc, float* __restrict__ E){
  __shared__ float Wf[5*512];
  int tid = threadIdx.x;
  for(int i=tid;i<5*512;i+=256) Wf[i] = Wfc[i];
  __syncthreads();
  int m = blockIdx.x*256 + tid;
  float a0=0,a1=0,a2=0,a3=0,a4=0;
  #pragma unroll 4
  for(int k=0;k<512;k++){
    float x = Xt[(size_t)k*MM + m];
    a0 += x*Wf[k]; a1 += x*Wf[512+k]; a2 += x*Wf[1024+k]; a3 += x*Wf[1536+k]; a4 += x*Wf[2048+k];
  }
  float* e = &E[(size_t)m*8];
  e[0]=a0+bfc[0]; e[1]=a1+bfc[1]; e[2]=a2+bfc[2]; e[3]=a3+bfc[3]; e[4]=a4+bfc[4];
}

// ---------------- features: feat[b][t][h] = Xt[h][t*64+b] (tile transpose) ----------------
__global__ __launch_bounds__(256) void k_feat(const float* __restrict__ Xt,
      float* __restrict__ feat){
  __shared__ float T[64][65];
  const int t = blockIdx.y, h0 = blockIdx.x*64;
  const int tid = threadIdx.x;
  const int hr = tid>>2, q = tid&3;
  const float* src = &Xt[(size_t)(h0+hr)*MM + (size_t)t*BB + q*16];
  #pragma unroll
  for(int i=0;i<4;i++){
    float4 v = *(const float4*)&src[i*4];
    T[hr][q*16+i*4+0]=v.x; T[hr][q*16+i*4+1]=v.y;
    T[hr][q*16+i*4+2]=v.z; T[hr][q*16+i*4+3]=v.w;
  }
  __syncthreads();
  float* dst = &feat[((size_t)hr*LL + t)*HID2 + h0 + q*16];
  #pragma unroll
  for(int i=0;i<16;i+=4){
    float4 v = {T[q*16+i+0][hr], T[q*16+i+1][hr], T[q*16+i+2][hr], T[q*16+i+3][hr]};
    *(float4*)&dst[i] = v;
  }
}

__global__ __launch_bounds__(256) void k_mask(float* __restrict__ masks){
  int id = blockIdx.x*256 + threadIdx.x;
  if(id < MM) masks[id] = 1.0f;
}

// ---------------- Viterbi: 1 block, 64 threads, prefetch-pipelined ----------------
__global__ __launch_bounds__(64) void k_viterbi(const float* __restrict__ E,
      const float* __restrict__ trans, float* __restrict__ out_score,
      float* __restrict__ out_tags){
  __shared__ uint16_t bps[LL*BB];
  const int b = threadIdx.x;
  float T[25];
  #pragma unroll
  for(int i=0;i<25;i++) T[i] = trans[i];
  float ms[5];
  #pragma unroll
  for(int c=0;c<5;c++) ms[c] = IMPOSSIBLE_V;
  ms[3] = 0.f;                               // START = 3
  float4 c0 = *(const float4*)&E[(size_t)b*8];
  float  c4 = E[(size_t)b*8 + 4];
  for(int t=0;t<LL;t++){
    float4 n0 = c0; float n4 = c4;
    if(t < LL-1){
      const float* e = &E[(size_t)((t+1)*BB + b)*8];
      n0 = *(const float4*)e; n4 = e[4];
    }
    float ee[5] = {c0.x, c0.y, c0.z, c0.w, c4};
    float ns[5]; int pack = 0;
    #pragma unroll
    for(int to=0;to<5;to++){
      float best = ms[0] + T[to*5+0]; int bi = 0;
      #pragma unroll
      for(int f=1;f<5;f++){
        float v = ms[f] + T[to*5+f];
        if(v > best){ best = v; bi = f; }   // strict > = first-max (jnp.argmax)
      }
      ns[to] = best + ee[to];
      pack |= bi << (3*to);
    }
    bps[t*BB + b] = (uint16_t)pack;
    #pragma unroll
    for(int c=0;c<5;c++) ms[c] = ns[c];
    c0 = n0; c4 = n4;
  }
  float best = ms[0] + T[4*5+0]; int tag = 0; // STOP = 4
  #pragma unroll
  for(int f=1;f<5;f++){
    float v = ms[f] + T[4*5+f];
    if(v > best){ best = v; tag = f; }
  }
  out_score[b] = best;
  out_tags[b*LL + (LL-1)] = (float)tag;
  for(int t=LL-1; t>=1; t--){
    tag = (bps[t*BB + b] >> (3*tag)) & 7;
    out_tags[b*LL + t-1] = (float)tag;
  }
}

extern "C" void kernel_launch(void* const* d_in, const int* in_sizes, int n_in,
                              void* d_out, int out_size, void* d_ws, size_t ws_size,
                              hipStream_t stream){
  const int*   xs    = (const int*)d_in[0];
  const float* emb   = (const float*)d_in[1];
  const float* Wih0  = (const float*)d_in[2];
  const float* Whh0  = (const float*)d_in[3];
  const float* b0    = (const float*)d_in[4];
  const float* WihL  = (const float*)d_in[5];
  const float* WhhL  = (const float*)d_in[6];
  const float* bL    = (const float*)d_in[7];
  const float* Wfc   = (const float*)d_in[8];
  const float* bfc   = (const float*)d_in[9];
  const float* trans = (const float*)d_in[10];

  char* ws = (char*)d_ws;
  int*   flags = (int*)ws;                                   // 2*64*16 ints = 8 KB
  float* hbuf  = (float*)(ws + 32768);                       // 4 * 16384 f32 = 256 KB
  float* cbuf  = (float*)(ws + 32768 + 262144);              // 2*256*64 f32 = 128 KB
  float* Xa    = (float*)(ws + (size_t)(1<<20));                             // 64 MB
  float* Xb    = (float*)(ws + (size_t)(1<<20) + ((size_t)MM*HID2*4));       // 64 MB
  float* G     = (float*)(ws + (size_t)(1<<20) + 2*((size_t)MM*HID2*4));     // 64 MB
  float* emitb = G;                                          // alias: G dead after scans

  hipMemsetAsync(flags, 0, 8192, stream);
  k_embed<<<8192, 256, 0, stream>>>(xs, emb, Xa);
  float* cur = Xa; float* nxt = Xb;
  for(int l=0;l<4;l++){
    int KD = (l==0) ? 256 : 512;
    const float* Wih = (l==0) ? Wih0 : WihL + (size_t)(l-1)*2*G4*HID2;
    const float* Whh = (l==0) ? Whh0 : WhhL + (size_t)(l-1)*2*G4*HH;
    const float* bb  = (l==0) ? b0   : bL  + (size_t)(l-1)*2*G4;
    for(int chunk=0; chunk<4; chunk++){
      int t0d0 = chunk*CH;
      int t0d1 = (LL-CH) - chunk*CH;
      k_ingemm<<<dim3(MROWS/128, G4/64, 2), 256, 0, stream>>>(cur, KD, Wih, bb, G, t0d0, t0d1);
      k_scan<<<dim3(64, 2), 256, 0, stream>>>(G, Whh, nxt, hbuf, cbuf, flags,
                                              chunk, (l*4+chunk)*CH, chunk==0 ? 1 : 0);
    }
    float* tmp = cur; cur = nxt; nxt = tmp;
  }
  k_emit<<<MM/256, 256, 0, stream>>>(cur, Wfc, bfc, emitb);
  float* out       = (float*)d_out;
  float* out_score = out;
  float* out_tags  = out + 64;
  float* out_feat  = out + 64 + MM;
  float* out_masks = out + 64 + MM + (size_t)MM*HID2;
  k_feat<<<dim3(HID2/64, LL), 256, 0, stream>>>(cur, out_feat);
  k_mask<<<MM/256, 256, 0, stream>>>(out_masks);
  k_viterbi<<<1, 64, 0, stream>>>(emitb, trans, out_score, out_tags);
}